// Round 1
// baseline (3444.458 us; speedup 1.0000x reference)
//
#include <hip/hip_runtime.h>

#define D 256
#define BM 32

// ---------------------------------------------------------------------------
// Phase 1: scatter-add raw x rows into G[col], count deg[col].
// One wave (64 lanes) per edge; each lane handles one float4 (16B) of the row.
// ---------------------------------------------------------------------------
__global__ void scatter_kernel(const float* __restrict__ x,
                               const int* __restrict__ row,
                               const int* __restrict__ col,
                               float* __restrict__ G,
                               int* __restrict__ deg,
                               int nEdges) {
    int gid = blockIdx.x * blockDim.x + threadIdx.x;
    int e = gid >> 6;           // one wave per edge
    int lane = threadIdx.x & 63;
    if (e >= nEdges) return;
    int r = row[e];
    int c = col[e];
    if (lane == 0) atomicAdd(&deg[c], 1);
    float4 v = ((const float4*)(x + (size_t)r * D))[lane];
    float* g = G + (size_t)c * D + lane * 4;
    atomicAdd(g + 0, v.x);
    atomicAdd(g + 1, v.y);
    atomicAdd(g + 2, v.z);
    atomicAdd(g + 3, v.w);
}

// ---------------------------------------------------------------------------
// Phase 2: fused triple-GEMM + epilogue.
// out[n,j] = sum_k x[n,k]*W_self[k,j] + G[n,k]*W_src[k,j]
//            - deg[n] * sum_k x[n,k]*W_dst[k,j]
//            + b_self[j] + deg[n]*(b_src[j]-b_dst[j])
// Block: 256 threads (thread = output column j), BM=32 rows per block.
// x/G tiles in LDS (broadcast reads), W streamed from L2 (coalesced over j),
// W reuse amortized over 32 rows in registers.
// ---------------------------------------------------------------------------
__global__ __launch_bounds__(256, 2) void fused_gemm(
    const float* __restrict__ x, const float* __restrict__ G,
    const int* __restrict__ deg,
    const float* __restrict__ Wsrc, const float* __restrict__ bsrc,
    const float* __restrict__ Wdst, const float* __restrict__ bdst,
    const float* __restrict__ Wself, const float* __restrict__ bself,
    float* __restrict__ out, int nNodes)
{
    __shared__ float xs[BM][D];
    __shared__ float Gs[BM][D];
    __shared__ float degs[BM];
    const int tid = threadIdx.x;
    const int base = blockIdx.x * BM;

    // cooperative tile load: 2048 float4s, 8 per thread, coalesced
    for (int i = tid; i < BM * (D / 4); i += 256) {
        int m = i / (D / 4);
        int k4 = i % (D / 4);
        int n = base + m;
        float4 xv = make_float4(0.f, 0.f, 0.f, 0.f);
        float4 gv = make_float4(0.f, 0.f, 0.f, 0.f);
        if (n < nNodes) {
            xv = ((const float4*)(x + (size_t)n * D))[k4];
            gv = ((const float4*)(G + (size_t)n * D))[k4];
        }
        ((float4*)xs[m])[k4] = xv;
        ((float4*)Gs[m])[k4] = gv;
    }
    if (tid < BM) {
        int n = base + tid;
        degs[tid] = (n < nNodes) ? (float)deg[n] : 0.f;
    }
    __syncthreads();

    const int j = tid;  // output column
    float acc1[BM];     // self + src contributions
    float acc2[BM];     // dst contribution (scaled by -deg in epilogue)
    #pragma unroll
    for (int m = 0; m < BM; ++m) { acc1[m] = 0.f; acc2[m] = 0.f; }

    for (int k = 0; k < D; k += 4) {
        float wse[4], wsr[4], wds[4];
        #pragma unroll
        for (int kk = 0; kk < 4; ++kk) {
            wse[kk] = Wself[(size_t)(k + kk) * D + j];
            wsr[kk] = Wsrc [(size_t)(k + kk) * D + j];
            wds[kk] = Wdst [(size_t)(k + kk) * D + j];
        }
        #pragma unroll
        for (int m = 0; m < BM; ++m) {
            float4 xv = ((const float4*)xs[m])[k / 4];  // wave-broadcast LDS read
            float4 gv = ((const float4*)Gs[m])[k / 4];
            acc1[m] += xv.x * wse[0] + xv.y * wse[1] + xv.z * wse[2] + xv.w * wse[3]
                     + gv.x * wsr[0] + gv.y * wsr[1] + gv.z * wsr[2] + gv.w * wsr[3];
            acc2[m] += xv.x * wds[0] + xv.y * wds[1] + xv.z * wds[2] + xv.w * wds[3];
        }
    }

    const float bs  = bself[j];
    const float dbb = bsrc[j] - bdst[j];
    #pragma unroll
    for (int m = 0; m < BM; ++m) {
        int n = base + m;
        if (n < nNodes) {
            float d = degs[m];
            out[(size_t)n * D + j] = acc1[m] - d * acc2[m] + bs + d * dbb;
        }
    }
}

extern "C" void kernel_launch(void* const* d_in, const int* in_sizes, int n_in,
                              void* d_out, int out_size, void* d_ws, size_t ws_size,
                              hipStream_t stream) {
    const float* x     = (const float*)d_in[0];
    const int*   eidx  = (const int*)d_in[1];
    const float* Wsrc  = (const float*)d_in[2];
    const float* bsrc  = (const float*)d_in[3];
    const float* Wdst  = (const float*)d_in[4];
    const float* bdst  = (const float*)d_in[5];
    const float* Wself = (const float*)d_in[6];
    const float* bself = (const float*)d_in[7];
    float* out = (float*)d_out;

    const int N = in_sizes[0] / D;       // 50000
    const int E = in_sizes[1] / 2;       // 800000
    const int* row = eidx;               // edge_index[0]
    const int* col = eidx + E;           // edge_index[1]

    // workspace layout: G [N*D f32] | deg [N i32]
    float* G = (float*)d_ws;
    int* deg = (int*)((char*)d_ws + (size_t)N * D * sizeof(float));
    size_t zero_bytes = (size_t)N * D * sizeof(float) + (size_t)N * sizeof(int);
    hipMemsetAsync(d_ws, 0, zero_bytes, stream);

    // scatter: one wave per edge
    {
        long long total_threads = (long long)E * 64;
        int block = 256;
        int grid = (int)((total_threads + block - 1) / block);
        scatter_kernel<<<grid, block, 0, stream>>>(x, row, col, G, deg, E);
    }

    // fused gemm + epilogue
    {
        int grid = (N + BM - 1) / BM;
        fused_gemm<<<grid, 256, 0, stream>>>(x, G, deg,
                                             Wsrc, bsrc, Wdst, bdst, Wself, bself,
                                             out, N);
    }
}

// Round 2
// 974.544 us; speedup vs baseline: 3.5344x; 3.5344x over previous
//
#include <hip/hip_runtime.h>

#define D 256
#define BM 32

// ---------------------------------------------------------------------------
// Phase 1a: integer degree histogram over destination nodes.
// ---------------------------------------------------------------------------
__global__ void deg_kernel(const int* __restrict__ col, int* __restrict__ deg, int E) {
    int e = blockIdx.x * blockDim.x + threadIdx.x;
    if (e < E) atomicAdd(&deg[col[e]], 1);
}

// ---------------------------------------------------------------------------
// Phase 1b: exclusive scan of deg -> off (and cursor copy). Single block.
// ---------------------------------------------------------------------------
__global__ __launch_bounds__(1024) void scan_kernel(const int* __restrict__ deg,
                                                    int* __restrict__ off,
                                                    int* __restrict__ cursor, int n) {
    __shared__ int buf[1024];
    __shared__ int carry;
    if (threadIdx.x == 0) carry = 0;
    __syncthreads();
    for (int base = 0; base < n; base += 1024) {
        int i = base + threadIdx.x;
        int v = (i < n) ? deg[i] : 0;
        buf[threadIdx.x] = v;
        __syncthreads();
        for (int s = 1; s < 1024; s <<= 1) {
            int t = (threadIdx.x >= (unsigned)s) ? buf[threadIdx.x - s] : 0;
            __syncthreads();
            buf[threadIdx.x] += t;
            __syncthreads();
        }
        int excl = buf[threadIdx.x] - v + carry;
        if (i < n) { off[i] = excl; cursor[i] = excl; }
        __syncthreads();                       // all reads of carry/buf done
        if (threadIdx.x == 1023) carry += buf[1023];
        __syncthreads();                       // carry visible before next chunk
    }
}

// ---------------------------------------------------------------------------
// Phase 1c: scatter edge source indices into per-destination buckets.
// ---------------------------------------------------------------------------
__global__ void bucket_kernel(const int* __restrict__ row, const int* __restrict__ col,
                              int* __restrict__ cursor, int* __restrict__ bucket, int E) {
    int e = blockIdx.x * blockDim.x + threadIdx.x;
    if (e >= E) return;
    int pos = atomicAdd(&cursor[col[e]], 1);
    bucket[pos] = row[e];
}

// ---------------------------------------------------------------------------
// Phase 1d: per-node gather-sum. One wave (64 lanes) per node; lane handles
// one float4 (16B) of the 1KB row. No float atomics; G written exactly once.
// ---------------------------------------------------------------------------
__global__ __launch_bounds__(256) void segsum_kernel(const float* __restrict__ x,
                                                     const int* __restrict__ off,
                                                     const int* __restrict__ deg,
                                                     const int* __restrict__ bucket,
                                                     float* __restrict__ G, int N) {
    int node = blockIdx.x * 4 + (threadIdx.x >> 6);
    int lane = threadIdx.x & 63;
    if (node >= N) return;
    int start = off[node];
    int cnt = deg[node];
    float4 acc = make_float4(0.f, 0.f, 0.f, 0.f);
    for (int i = 0; i < cnt; ++i) {
        int r = bucket[start + i];                       // wave-broadcast load
        float4 v = ((const float4*)(x + (size_t)r * D))[lane];
        acc.x += v.x; acc.y += v.y; acc.z += v.z; acc.w += v.w;
    }
    ((float4*)(G + (size_t)node * D))[lane] = acc;
}

// ---------------------------------------------------------------------------
// Phase 2: fused triple-GEMM + epilogue (unchanged from round 1).
// out[n,j] = x@W_self + G@W_src - deg*(x@W_dst) + b_self + deg*(b_src-b_dst)
// ---------------------------------------------------------------------------
__global__ __launch_bounds__(256, 2) void fused_gemm(
    const float* __restrict__ x, const float* __restrict__ G,
    const int* __restrict__ deg,
    const float* __restrict__ Wsrc, const float* __restrict__ bsrc,
    const float* __restrict__ Wdst, const float* __restrict__ bdst,
    const float* __restrict__ Wself, const float* __restrict__ bself,
    float* __restrict__ out, int nNodes)
{
    __shared__ float xs[BM][D];
    __shared__ float Gs[BM][D];
    __shared__ float degs[BM];
    const int tid = threadIdx.x;
    const int base = blockIdx.x * BM;

    for (int i = tid; i < BM * (D / 4); i += 256) {
        int m = i / (D / 4);
        int k4 = i % (D / 4);
        int n = base + m;
        float4 xv = make_float4(0.f, 0.f, 0.f, 0.f);
        float4 gv = make_float4(0.f, 0.f, 0.f, 0.f);
        if (n < nNodes) {
            xv = ((const float4*)(x + (size_t)n * D))[k4];
            gv = ((const float4*)(G + (size_t)n * D))[k4];
        }
        ((float4*)xs[m])[k4] = xv;
        ((float4*)Gs[m])[k4] = gv;
    }
    if (tid < BM) {
        int n = base + tid;
        degs[tid] = (n < nNodes) ? (float)deg[n] : 0.f;
    }
    __syncthreads();

    const int j = tid;
    float acc1[BM];
    float acc2[BM];
    #pragma unroll
    for (int m = 0; m < BM; ++m) { acc1[m] = 0.f; acc2[m] = 0.f; }

    for (int k = 0; k < D; k += 4) {
        float wse[4], wsr[4], wds[4];
        #pragma unroll
        for (int kk = 0; kk < 4; ++kk) {
            wse[kk] = Wself[(size_t)(k + kk) * D + j];
            wsr[kk] = Wsrc [(size_t)(k + kk) * D + j];
            wds[kk] = Wdst [(size_t)(k + kk) * D + j];
        }
        #pragma unroll
        for (int m = 0; m < BM; ++m) {
            float4 xv = ((const float4*)xs[m])[k / 4];
            float4 gv = ((const float4*)Gs[m])[k / 4];
            acc1[m] += xv.x * wse[0] + xv.y * wse[1] + xv.z * wse[2] + xv.w * wse[3]
                     + gv.x * wsr[0] + gv.y * wsr[1] + gv.z * wsr[2] + gv.w * wsr[3];
            acc2[m] += xv.x * wds[0] + xv.y * wds[1] + xv.z * wds[2] + xv.w * wds[3];
        }
    }

    const float bs  = bself[j];
    const float dbb = bsrc[j] - bdst[j];
    #pragma unroll
    for (int m = 0; m < BM; ++m) {
        int n = base + m;
        if (n < nNodes) {
            float d = degs[m];
            out[(size_t)n * D + j] = acc1[m] - d * acc2[m] + bs + d * dbb;
        }
    }
}

extern "C" void kernel_launch(void* const* d_in, const int* in_sizes, int n_in,
                              void* d_out, int out_size, void* d_ws, size_t ws_size,
                              hipStream_t stream) {
    const float* x     = (const float*)d_in[0];
    const int*   eidx  = (const int*)d_in[1];
    const float* Wsrc  = (const float*)d_in[2];
    const float* bsrc  = (const float*)d_in[3];
    const float* Wdst  = (const float*)d_in[4];
    const float* bdst  = (const float*)d_in[5];
    const float* Wself = (const float*)d_in[6];
    const float* bself = (const float*)d_in[7];
    float* out = (float*)d_out;

    const int N = in_sizes[0] / D;       // 50000
    const int E = in_sizes[1] / 2;       // 800000
    const int* row = eidx;               // edge_index[0]
    const int* col = eidx + E;           // edge_index[1]

    // workspace layout: G [N*D f32] | deg [N i32] | off [N i32] | cursor [N i32] | bucket [E i32]
    char* p = (char*)d_ws;
    float* G     = (float*)p;                 p += (size_t)N * D * sizeof(float);
    int*   deg   = (int*)p;                   p += (size_t)N * sizeof(int);
    int*   off   = (int*)p;                   p += (size_t)N * sizeof(int);
    int*   cursor= (int*)p;                   p += (size_t)N * sizeof(int);
    int*   bucket= (int*)p;

    // zero only deg (scan/bucket/segsum fully overwrite the rest)
    hipMemsetAsync(deg, 0, (size_t)N * sizeof(int), stream);

    deg_kernel<<<(E + 255) / 256, 256, 0, stream>>>(col, deg, E);
    scan_kernel<<<1, 1024, 0, stream>>>(deg, off, cursor, N);
    bucket_kernel<<<(E + 255) / 256, 256, 0, stream>>>(row, col, cursor, bucket, E);
    segsum_kernel<<<(N + 3) / 4, 256, 0, stream>>>(x, off, deg, bucket, G, N);

    fused_gemm<<<(N + BM - 1) / BM, 256, 0, stream>>>(x, G, deg,
                                                      Wsrc, bsrc, Wdst, bdst, Wself, bself,
                                                      out, N);
}

// Round 3
// 406.594 us; speedup vs baseline: 8.4715x; 2.3968x over previous
//
#include <hip/hip_runtime.h>

#define D 256

typedef unsigned short ushort_t;
typedef unsigned int uint_t;
typedef __attribute__((ext_vector_type(8))) short short8;
typedef __attribute__((ext_vector_type(4))) float floatx4;

static __device__ __forceinline__ ushort_t f2bf(float f) {
    union { float f; uint_t u; } c; c.f = f;
    uint_t r = (c.u + 0x7FFFu + ((c.u >> 16) & 1u)) >> 16;   // RN-even
    return (ushort_t)r;
}
static __device__ __forceinline__ float bf2f(ushort_t b) {
    union { uint_t u; float f; } c; c.u = ((uint_t)b) << 16;
    return c.f;
}

// ---------------------------------------------------------------------------
// Phase 1a: integer degree histogram over destination nodes.
// ---------------------------------------------------------------------------
__global__ void deg_kernel(const int* __restrict__ col, int* __restrict__ deg, int E) {
    int e = blockIdx.x * blockDim.x + threadIdx.x;
    if (e < E) atomicAdd(&deg[col[e]], 1);
}

// ---------------------------------------------------------------------------
// Phase 1b: exclusive scan of deg -> off/cursor. Single block, shfl wave scans.
// ---------------------------------------------------------------------------
__global__ __launch_bounds__(1024) void scan_kernel(const int* __restrict__ deg,
                                                    int* __restrict__ off,
                                                    int* __restrict__ cursor, int n) {
    __shared__ int wsum[16];
    __shared__ int chunk_total;
    __shared__ int carry_s;
    const int tid = threadIdx.x, lane = tid & 63, wid = tid >> 6;
    if (tid == 0) carry_s = 0;
    __syncthreads();
    for (int base = 0; base < n; base += 1024) {
        int i = base + tid;
        int v = (i < n) ? deg[i] : 0;
        int incl = v;
        #pragma unroll
        for (int s = 1; s < 64; s <<= 1) {
            int t = __shfl_up(incl, s, 64);
            if (lane >= s) incl += t;
        }
        if (lane == 63) wsum[wid] = incl;
        __syncthreads();
        if (wid == 0) {
            int wv = (lane < 16) ? wsum[lane] : 0;
            int wincl = wv;
            #pragma unroll
            for (int s = 1; s < 16; s <<= 1) {
                int t = __shfl_up(wincl, s, 64);
                if (lane >= s) wincl += t;
            }
            if (lane < 16) wsum[lane] = wincl - wv;   // exclusive wave offsets
            if (lane == 15) chunk_total = wincl;
        }
        __syncthreads();
        int excl = incl - v + wsum[wid] + carry_s;
        if (i < n) { off[i] = excl; cursor[i] = excl; }
        __syncthreads();
        if (tid == 0) carry_s += chunk_total;
        __syncthreads();
    }
}

// ---------------------------------------------------------------------------
// Phase 1c: scatter edge source indices into per-destination buckets.
// ---------------------------------------------------------------------------
__global__ void bucket_kernel(const int* __restrict__ row, const int* __restrict__ col,
                              int* __restrict__ cursor, int* __restrict__ bucket, int E) {
    int e = blockIdx.x * blockDim.x + threadIdx.x;
    if (e >= E) return;
    int pos = atomicAdd(&cursor[col[e]], 1);
    bucket[pos] = row[e];
}

// ---------------------------------------------------------------------------
// Phase 1d: x -> bf16 copy (xh). One thread per 8 floats.
// ---------------------------------------------------------------------------
__global__ void convert_x(const float* __restrict__ x, ushort_t* __restrict__ xh, int total8) {
    int i = blockIdx.x * blockDim.x + threadIdx.x;
    if (i >= total8) return;
    float4 a = ((const float4*)x)[i * 2];
    float4 b = ((const float4*)x)[i * 2 + 1];
    uint4 o;
    o.x = f2bf(a.x) | ((uint_t)f2bf(a.y) << 16);
    o.y = f2bf(a.z) | ((uint_t)f2bf(a.w) << 16);
    o.z = f2bf(b.x) | ((uint_t)f2bf(b.y) << 16);
    o.w = f2bf(b.z) | ((uint_t)f2bf(b.w) << 16);
    ((uint4*)xh)[i] = o;
}

// ---------------------------------------------------------------------------
// Phase 1e: per-node gather-sum, fp32 accumulate, bf16 output.
// One wave per node; lane handles 4 consecutive floats.
// ---------------------------------------------------------------------------
__global__ __launch_bounds__(256) void segsum_kernel(const float* __restrict__ x,
                                                     const int* __restrict__ off,
                                                     const int* __restrict__ deg,
                                                     const int* __restrict__ bucket,
                                                     ushort_t* __restrict__ Gh, int N) {
    int node = blockIdx.x * 4 + (threadIdx.x >> 6);
    int lane = threadIdx.x & 63;
    if (node >= N) return;
    int start = off[node];
    int cnt = deg[node];
    float4 acc = make_float4(0.f, 0.f, 0.f, 0.f);
    for (int i = 0; i < cnt; ++i) {
        int r = bucket[start + i];                       // wave-broadcast load
        float4 v = ((const float4*)(x + (size_t)r * D))[lane];
        acc.x += v.x; acc.y += v.y; acc.z += v.z; acc.w += v.w;
    }
    ushort4 o;
    o.x = f2bf(acc.x); o.y = f2bf(acc.y); o.z = f2bf(acc.z); o.w = f2bf(acc.w);
    ((ushort4*)(Gh + (size_t)node * D))[lane] = o;
}

// ---------------------------------------------------------------------------
// Phase 1f: build BT[j][k] (N-major, bf16), k in [0,768):
//   k<256: W_self[k][j]; k<512: W_src[k-256][j]; else: -W_dst[k-512][j]
// ---------------------------------------------------------------------------
__global__ void prep_BT(const float* __restrict__ Wself, const float* __restrict__ Wsrc,
                        const float* __restrict__ Wdst, ushort_t* __restrict__ BT) {
    int id = blockIdx.x * blockDim.x + threadIdx.x;   // 256*768 ids: j*768+k
    if (id >= 256 * 768) return;
    int j = id / 768, k = id % 768;
    float v;
    if (k < 256)      v =  Wself[(size_t)k * 256 + j];
    else if (k < 512) v =  Wsrc [(size_t)(k - 256) * 256 + j];
    else              v = -Wdst [(size_t)(k - 512) * 256 + j];
    BT[id] = f2bf(v);
}

// ---------------------------------------------------------------------------
// Phase 2: bf16 MFMA GEMM.  out[M=50000, N=256] = A[M, K=768] @ B[K, 256]
//   A = [ xh | Gh | deg*xh ] (deg scaling applied at staging time)
//   B  via BT (N-major).  Epilogue: + bself[j] + deg[m]*(bsrc[j]-bdst[j]).
// 128x128 tile / block, 4 waves 2x2, each wave 4x4 of 16x16x32 MFMA.
// LDS rows padded to 80B -> 2-way conflicts only (free).
// ---------------------------------------------------------------------------
__global__ __launch_bounds__(256, 2) void mfma_gemm(
    const ushort_t* __restrict__ xh, const ushort_t* __restrict__ Gh,
    const ushort_t* __restrict__ BT, const int* __restrict__ deg,
    const float* __restrict__ bsrc, const float* __restrict__ bdst,
    const float* __restrict__ bself, float* __restrict__ out, int N)
{
    __shared__ ushort_t As[128][40];   // 32 bf16 cols + 8 pad (80B stride)
    __shared__ ushort_t Bs[128][40];

    const int tid = threadIdx.x;
    const int lane = tid & 63, wave = tid >> 6;
    const int quad = lane >> 4, l15 = lane & 15;
    const int m0 = (wave >> 1) * 64, n0 = (wave & 1) * 64;
    const int mbase = blockIdx.x * 128, nbase = blockIdx.y * 128;

    floatx4 acc[4][4] = {};

    for (int kt = 0; kt < 24; ++kt) {
        const int kcol = (kt & 7) * 32;
        const ushort_t* Asrc = (kt < 8) ? xh : (kt < 16) ? Gh : xh;
        const bool scale = (kt >= 16);

        #pragma unroll
        for (int h = 0; h < 2; ++h) {
            int c = tid + h * 256;            // 512 chunks of 16B
            int row = c >> 2, cc = c & 3;
            int gr = mbase + row; if (gr >= N) gr = N - 1;   // clamp; masked at store
            uint4 v = *(const uint4*)(Asrc + (size_t)gr * 256 + kcol + cc * 8);
            if (scale) {
                float dscale = (float)deg[gr];
                uint_t vv[4] = {v.x, v.y, v.z, v.w};
                #pragma unroll
                for (int q = 0; q < 4; ++q) {
                    ushort_t lo = (ushort_t)(vv[q] & 0xFFFFu);
                    ushort_t hi = (ushort_t)(vv[q] >> 16);
                    vv[q] = (uint_t)f2bf(bf2f(lo) * dscale)
                          | ((uint_t)f2bf(bf2f(hi) * dscale) << 16);
                }
                v = make_uint4(vv[0], vv[1], vv[2], vv[3]);
            }
            *(uint4*)(&As[row][cc * 8]) = v;

            int gn = nbase + row;             // N-dim is exactly 256: no clamp needed
            uint4 w = *(const uint4*)(BT + (size_t)gn * 768 + kt * 32 + cc * 8);
            *(uint4*)(&Bs[row][cc * 8]) = w;
        }
        __syncthreads();

        short8 af[4], bfr[4];
        #pragma unroll
        for (int im = 0; im < 4; ++im)
            af[im] = *(const short8*)(&As[m0 + im * 16 + l15][quad * 8]);
        #pragma unroll
        for (int in = 0; in < 4; ++in)
            bfr[in] = *(const short8*)(&Bs[n0 + in * 16 + l15][quad * 8]);
        #pragma unroll
        for (int im = 0; im < 4; ++im)
            #pragma unroll
            for (int in = 0; in < 4; ++in)
                acc[im][in] = __builtin_amdgcn_mfma_f32_16x16x32_bf16(
                    af[im], bfr[in], acc[im][in], 0, 0, 0);
        __syncthreads();
    }

    // epilogue: C/D layout col=lane&15, row=quad*4+reg
    #pragma unroll
    for (int in = 0; in < 4; ++in) {
        int gn = nbase + n0 + in * 16 + l15;
        float bs = bself[gn];
        float db = bsrc[gn] - bdst[gn];
        #pragma unroll
        for (int im = 0; im < 4; ++im) {
            #pragma unroll
            for (int r = 0; r < 4; ++r) {
                int gm = mbase + m0 + im * 16 + quad * 4 + r;
                if (gm < N)
                    out[(size_t)gm * 256 + gn] = acc[im][in][r] + bs + (float)deg[gm] * db;
            }
        }
    }
}

extern "C" void kernel_launch(void* const* d_in, const int* in_sizes, int n_in,
                              void* d_out, int out_size, void* d_ws, size_t ws_size,
                              hipStream_t stream) {
    const float* x     = (const float*)d_in[0];
    const int*   eidx  = (const int*)d_in[1];
    const float* Wsrc  = (const float*)d_in[2];
    const float* bsrc  = (const float*)d_in[3];
    const float* Wdst  = (const float*)d_in[4];
    const float* bdst  = (const float*)d_in[5];
    const float* Wself = (const float*)d_in[6];
    const float* bself = (const float*)d_in[7];
    float* out = (float*)d_out;

    const int N = in_sizes[0] / D;       // 50000
    const int E = in_sizes[1] / 2;       // 800000
    const int* row = eidx;               // edge_index[0]
    const int* col = eidx + E;           // edge_index[1]

    // ws layout: xh | Gh | BT | deg | off | cursor | bucket
    char* p = (char*)d_ws;
    ushort_t* xh  = (ushort_t*)p;        p += (size_t)N * D * sizeof(ushort_t);
    ushort_t* Gh  = (ushort_t*)p;        p += (size_t)N * D * sizeof(ushort_t);
    ushort_t* BT  = (ushort_t*)p;        p += (size_t)768 * 256 * sizeof(ushort_t);
    int* deg      = (int*)p;             p += (size_t)N * sizeof(int);
    int* off      = (int*)p;             p += (size_t)N * sizeof(int);
    int* cursor   = (int*)p;             p += (size_t)N * sizeof(int);
    int* bucket   = (int*)p;

    hipMemsetAsync(deg, 0, (size_t)N * sizeof(int), stream);

    deg_kernel<<<(E + 255) / 256, 256, 0, stream>>>(col, deg, E);
    scan_kernel<<<1, 1024, 0, stream>>>(deg, off, cursor, N);
    bucket_kernel<<<(E + 255) / 256, 256, 0, stream>>>(row, col, cursor, bucket, E);
    convert_x<<<(N * D / 8 + 255) / 256, 256, 0, stream>>>(x, xh, N * D / 8);
    segsum_kernel<<<(N + 3) / 4, 256, 0, stream>>>(x, off, deg, bucket, Gh, N);
    prep_BT<<<(256 * 768 + 255) / 256, 256, 0, stream>>>(Wself, Wsrc, Wdst, BT);

    dim3 grid((N + 127) / 128, 2);
    mfma_gemm<<<grid, 256, 0, stream>>>(xh, Gh, BT, deg, bsrc, bdst, bself, out, N);
}

// Round 4
// 317.740 us; speedup vs baseline: 10.8405x; 1.2796x over previous
//
#include <hip/hip_runtime.h>

#define D 256

typedef unsigned short ushort_t;
typedef unsigned int uint_t;
typedef __attribute__((ext_vector_type(8))) short short8;
typedef __attribute__((ext_vector_type(4))) float floatx4;

static __device__ __forceinline__ ushort_t f2bf(float f) {
    union { float f; uint_t u; } c; c.f = f;
    uint_t r = (c.u + 0x7FFFu + ((c.u >> 16) & 1u)) >> 16;   // RN-even
    return (ushort_t)r;
}
static __device__ __forceinline__ float bf2f(ushort_t b) {
    union { uint_t u; float f; } c; c.u = ((uint_t)b) << 16;
    return c.f;
}

// ---------------------------------------------------------------------------
// Fused prep: [0,degB) deg histogram | [degB,degB+cvtB) x->bf16 | rest: BT.
// BT[j][k], j-major (stride 768): k<256 Wself[k][j], k<512 Wsrc[k-256][j],
// k<768 Wdst[k-512][j]  (POSITIVE Wdst; sign applied in GEMM epilogue).
// ---------------------------------------------------------------------------
__global__ void prep_kernel(const int* __restrict__ col, int* __restrict__ deg,
                            const float* __restrict__ x, ushort_t* __restrict__ xh,
                            const float* __restrict__ Wself, const float* __restrict__ Wsrc,
                            const float* __restrict__ Wdst, ushort_t* __restrict__ BT,
                            int E, int total8, int degB, int cvtB) {
    int b = blockIdx.x;
    if (b < degB) {
        int e = b * 256 + threadIdx.x;
        if (e < E) atomicAdd(&deg[col[e]], 1);
    } else if (b < degB + cvtB) {
        int i = (b - degB) * 256 + threadIdx.x;
        if (i >= total8) return;
        float4 a = ((const float4*)x)[i * 2];
        float4 bb = ((const float4*)x)[i * 2 + 1];
        uint4 o;
        o.x = f2bf(a.x) | ((uint_t)f2bf(a.y) << 16);
        o.y = f2bf(a.z) | ((uint_t)f2bf(a.w) << 16);
        o.z = f2bf(bb.x) | ((uint_t)f2bf(bb.y) << 16);
        o.w = f2bf(bb.z) | ((uint_t)f2bf(bb.w) << 16);
        ((uint4*)xh)[i] = o;
    } else {
        int id = (b - degB - cvtB) * 256 + threadIdx.x;   // j*768+k
        if (id >= 256 * 768) return;
        int j = id / 768, k = id % 768;
        float v;
        if (k < 256)      v = Wself[(size_t)k * 256 + j];
        else if (k < 512) v = Wsrc [(size_t)(k - 256) * 256 + j];
        else              v = Wdst [(size_t)(k - 512) * 256 + j];
        BT[id] = f2bf(v);
    }
}

// ---------------------------------------------------------------------------
// Exclusive scan of deg -> off/cursor. Single block, 4 elems/thread (int4).
// ---------------------------------------------------------------------------
__global__ __launch_bounds__(1024) void scan_kernel(const int* __restrict__ deg,
                                                    int* __restrict__ off,
                                                    int* __restrict__ cursor, int n4) {
    __shared__ int wsum[16];
    __shared__ int chunk_total;
    __shared__ int carry_s;
    const int tid = threadIdx.x, lane = tid & 63, wid = tid >> 6;
    if (tid == 0) carry_s = 0;
    __syncthreads();
    for (int base4 = 0; base4 < n4; base4 += 1024) {
        int i4 = base4 + tid;
        int4 v = (i4 < n4) ? ((const int4*)deg)[i4] : make_int4(0, 0, 0, 0);
        int s = v.x + v.y + v.z + v.w;
        int incl = s;
        #pragma unroll
        for (int st = 1; st < 64; st <<= 1) {
            int t = __shfl_up(incl, st, 64);
            if (lane >= st) incl += t;
        }
        if (lane == 63) wsum[wid] = incl;
        __syncthreads();
        if (wid == 0) {
            int wv = (lane < 16) ? wsum[lane] : 0;
            int wincl = wv;
            #pragma unroll
            for (int st = 1; st < 16; st <<= 1) {
                int t = __shfl_up(wincl, st, 64);
                if (lane >= st) wincl += t;
            }
            if (lane < 16) wsum[lane] = wincl - wv;
            if (lane == 15) chunk_total = wincl;
        }
        __syncthreads();
        int excl = incl - s + wsum[wid] + carry_s;
        if (i4 < n4) {
            int4 o;
            o.x = excl; o.y = o.x + v.x; o.z = o.y + v.y; o.w = o.z + v.z;
            ((int4*)off)[i4] = o;
            ((int4*)cursor)[i4] = o;
        }
        __syncthreads();
        if (tid == 0) carry_s += chunk_total;
        __syncthreads();
    }
}

// ---------------------------------------------------------------------------
// Bucket fill: bucket[cursor[col]++] = row.
// ---------------------------------------------------------------------------
__global__ void bucket_kernel(const int* __restrict__ row, const int* __restrict__ col,
                              int* __restrict__ cursor, int* __restrict__ bucket, int E) {
    int e = blockIdx.x * blockDim.x + threadIdx.x;
    if (e >= E) return;
    int pos = atomicAdd(&cursor[col[e]], 1);
    bucket[pos] = row[e];
}

// ---------------------------------------------------------------------------
// Per-node gather-sum over bf16 rows (512B each), fp32 accum, bf16 out.
// One wave per node; lane handles 4 consecutive bf16 (8B). 2-wide unroll
// for memory-level parallelism.
// ---------------------------------------------------------------------------
__global__ __launch_bounds__(256) void segsum_kernel(const ushort_t* __restrict__ xh,
                                                     const int* __restrict__ off,
                                                     const int* __restrict__ deg,
                                                     const int* __restrict__ bucket,
                                                     ushort_t* __restrict__ Gh, int N) {
    int node = blockIdx.x * 4 + (threadIdx.x >> 6);
    int lane = threadIdx.x & 63;
    if (node >= N) return;
    int start = off[node];
    int cnt = deg[node];
    float a0 = 0.f, a1 = 0.f, a2 = 0.f, a3 = 0.f;
    int i = 0;
    for (; i + 2 <= cnt; i += 2) {
        int r0 = bucket[start + i];
        int r1 = bucket[start + i + 1];
        ushort4 v0 = ((const ushort4*)(xh + (size_t)r0 * D))[lane];
        ushort4 v1 = ((const ushort4*)(xh + (size_t)r1 * D))[lane];
        a0 += bf2f(v0.x) + bf2f(v1.x);
        a1 += bf2f(v0.y) + bf2f(v1.y);
        a2 += bf2f(v0.z) + bf2f(v1.z);
        a3 += bf2f(v0.w) + bf2f(v1.w);
    }
    if (i < cnt) {
        int r0 = bucket[start + i];
        ushort4 v0 = ((const ushort4*)(xh + (size_t)r0 * D))[lane];
        a0 += bf2f(v0.x); a1 += bf2f(v0.y); a2 += bf2f(v0.z); a3 += bf2f(v0.w);
    }
    ushort4 o;
    o.x = f2bf(a0); o.y = f2bf(a1); o.z = f2bf(a2); o.w = f2bf(a3);
    ((ushort4*)(Gh + (size_t)node * D))[lane] = o;
}

// ---------------------------------------------------------------------------
// bf16 MFMA GEMM, dual accumulator:
//   acc1[M,256] = [xh|Gh] @ [Wself;Wsrc]   (K=512, kt 0..15)
//   acc2[M,256] = xh @ Wdst                (K=256, kt 0..7, reuses A-frags)
//   out = acc1 - deg*acc2 + bself + deg*(bsrc-bdst)
// 128x128 tile, 4 waves 2x2, each wave 4x4 of 16x16x32 MFMA.
// LDS rows padded to 80B (2-way bank aliasing only = free).
// ---------------------------------------------------------------------------
__global__ __launch_bounds__(256, 2) void mfma_gemm(
    const ushort_t* __restrict__ xh, const ushort_t* __restrict__ Gh,
    const ushort_t* __restrict__ BT, const int* __restrict__ deg,
    const float* __restrict__ bsrc, const float* __restrict__ bdst,
    const float* __restrict__ bself, float* __restrict__ out, int N)
{
    __shared__ ushort_t As[128][40];
    __shared__ ushort_t Bs[128][40];
    __shared__ ushort_t Ds[128][40];

    const int tid = threadIdx.x;
    const int lane = tid & 63, wave = tid >> 6;
    const int quad = lane >> 4, l15 = lane & 15;
    const int m0 = (wave >> 1) * 64, n0 = (wave & 1) * 64;
    const int mbase = blockIdx.x * 128, nbase = blockIdx.y * 128;

    floatx4 acc1[4][4] = {};
    floatx4 acc2[4][4] = {};

    for (int kt = 0; kt < 16; ++kt) {
        const int kcol = (kt & 7) * 32;
        const ushort_t* Asrc = (kt < 8) ? xh : Gh;

        #pragma unroll
        for (int h = 0; h < 2; ++h) {
            int c = tid + h * 256;
            int row = c >> 2, cc = c & 3;
            int gr = mbase + row; if (gr >= N) gr = N - 1;
            uint4 v = *(const uint4*)(Asrc + (size_t)gr * 256 + kcol + cc * 8);
            *(uint4*)(&As[row][cc * 8]) = v;
            int gn = nbase + row;
            uint4 w = *(const uint4*)(BT + (size_t)gn * 768 + kt * 32 + cc * 8);
            *(uint4*)(&Bs[row][cc * 8]) = w;
            if (kt < 8) {
                uint4 d = *(const uint4*)(BT + (size_t)gn * 768 + 512 + kt * 32 + cc * 8);
                *(uint4*)(&Ds[row][cc * 8]) = d;
            }
        }
        __syncthreads();

        short8 af[4], bfr[4];
        #pragma unroll
        for (int im = 0; im < 4; ++im)
            af[im] = *(const short8*)(&As[m0 + im * 16 + l15][quad * 8]);
        #pragma unroll
        for (int in = 0; in < 4; ++in)
            bfr[in] = *(const short8*)(&Bs[n0 + in * 16 + l15][quad * 8]);
        #pragma unroll
        for (int im = 0; im < 4; ++im)
            #pragma unroll
            for (int in = 0; in < 4; ++in)
                acc1[im][in] = __builtin_amdgcn_mfma_f32_16x16x32_bf16(
                    af[im], bfr[in], acc1[im][in], 0, 0, 0);
        if (kt < 8) {
            short8 df[4];
            #pragma unroll
            for (int in = 0; in < 4; ++in)
                df[in] = *(const short8*)(&Ds[n0 + in * 16 + l15][quad * 8]);
            #pragma unroll
            for (int im = 0; im < 4; ++im)
                #pragma unroll
                for (int in = 0; in < 4; ++in)
                    acc2[im][in] = __builtin_amdgcn_mfma_f32_16x16x32_bf16(
                        af[im], df[in], acc2[im][in], 0, 0, 0);
        }
        __syncthreads();
    }

    // hoist deg for the 16 distinct rows this thread writes
    float degv[4][4];
    #pragma unroll
    for (int im = 0; im < 4; ++im)
        #pragma unroll
        for (int r = 0; r < 4; ++r) {
            int gm = mbase + m0 + im * 16 + quad * 4 + r;
            degv[im][r] = (gm < N) ? (float)deg[gm] : 0.f;
        }

    // C/D layout: col=lane&15, row=quad*4+reg
    #pragma unroll
    for (int in = 0; in < 4; ++in) {
        int gn = nbase + n0 + in * 16 + l15;
        float bs = bself[gn];
        float db = bsrc[gn] - bdst[gn];
        #pragma unroll
        for (int im = 0; im < 4; ++im) {
            #pragma unroll
            for (int r = 0; r < 4; ++r) {
                int gm = mbase + m0 + im * 16 + quad * 4 + r;
                if (gm < N) {
                    float d = degv[im][r];
                    out[(size_t)gm * 256 + gn] =
                        acc1[im][in][r] - d * acc2[im][in][r] + bs + d * db;
                }
            }
        }
    }
}

extern "C" void kernel_launch(void* const* d_in, const int* in_sizes, int n_in,
                              void* d_out, int out_size, void* d_ws, size_t ws_size,
                              hipStream_t stream) {
    const float* x     = (const float*)d_in[0];
    const int*   eidx  = (const int*)d_in[1];
    const float* Wsrc  = (const float*)d_in[2];
    const float* bsrc  = (const float*)d_in[3];
    const float* Wdst  = (const float*)d_in[4];
    const float* bdst  = (const float*)d_in[5];
    const float* Wself = (const float*)d_in[6];
    const float* bself = (const float*)d_in[7];
    float* out = (float*)d_out;

    const int N = in_sizes[0] / D;       // 50000
    const int E = in_sizes[1] / 2;       // 800000
    const int* row = eidx;               // edge_index[0]
    const int* col = eidx + E;           // edge_index[1]

    // ws layout: xh | Gh | BT | deg | off | cursor | bucket
    char* p = (char*)d_ws;
    ushort_t* xh  = (ushort_t*)p;        p += (size_t)N * D * sizeof(ushort_t);
    ushort_t* Gh  = (ushort_t*)p;        p += (size_t)N * D * sizeof(ushort_t);
    ushort_t* BT  = (ushort_t*)p;        p += (size_t)768 * 256 * sizeof(ushort_t);
    int* deg      = (int*)p;             p += (size_t)N * sizeof(int);
    int* off      = (int*)p;             p += (size_t)N * sizeof(int);
    int* cursor   = (int*)p;             p += (size_t)N * sizeof(int);
    int* bucket   = (int*)p;

    hipMemsetAsync(deg, 0, (size_t)N * sizeof(int), stream);

    const int total8 = N * D / 8;
    const int degB = (E + 255) / 256;
    const int cvtB = (total8 + 255) / 256;
    const int btB  = (256 * 768 + 255) / 256;
    prep_kernel<<<degB + cvtB + btB, 256, 0, stream>>>(col, deg, x, xh,
                                                       Wself, Wsrc, Wdst, BT,
                                                       E, total8, degB, cvtB);
    scan_kernel<<<1, 1024, 0, stream>>>(deg, off, cursor, N / 4);
    bucket_kernel<<<(E + 255) / 256, 256, 0, stream>>>(row, col, cursor, bucket, E);
    segsum_kernel<<<(N + 3) / 4, 256, 0, stream>>>(xh, off, deg, bucket, Gh, N);

    dim3 grid((N + 127) / 128, 2);
    mfma_gemm<<<grid, 256, 0, stream>>>(xh, Gh, BT, deg, bsrc, bdst, bself, out, N);
}

// Round 5
// 281.880 us; speedup vs baseline: 12.2196x; 1.1272x over previous
//
#include <hip/hip_runtime.h>

#define D 256

typedef unsigned short ushort_t;
typedef unsigned int uint_t;
typedef __attribute__((ext_vector_type(8))) short short8;
typedef __attribute__((ext_vector_type(4))) float floatx4;

static __device__ __forceinline__ ushort_t f2bf(float f) {
    union { float f; uint_t u; } c; c.f = f;
    uint_t r = (c.u + 0x7FFFu + ((c.u >> 16) & 1u)) >> 16;   // RN-even
    return (ushort_t)r;
}
static __device__ __forceinline__ float bf2f(ushort_t b) {
    union { uint_t u; float f; } c; c.u = ((uint_t)b) << 16;
    return c.f;
}

// async global->LDS DMA, 16B per lane, dest = uniform base + lane*16
static __device__ __forceinline__ void async16(const void* g, void* l) {
    __builtin_amdgcn_global_load_lds(
        (const __attribute__((address_space(1))) void*)g,
        (__attribute__((address_space(3))) void*)l, 16, 0, 0);
}

// ---------------------------------------------------------------------------
// Fused prep, 3 grid sections:
//  [0,degB):      rank[e] = atomicAdd(&deg[col[e]],1)  (histogram + edge rank)
//  [degB,+cvtB):  x -> bf16 (xh)
//  rest:          BT[j][k] j-major: k<256 Wself[k][j] | k<512 Wsrc | k<768 Wdst
// ---------------------------------------------------------------------------
__global__ void prep_kernel(const int* __restrict__ col, int* __restrict__ deg,
                            int* __restrict__ rank,
                            const float* __restrict__ x, ushort_t* __restrict__ xh,
                            const float* __restrict__ Wself, const float* __restrict__ Wsrc,
                            const float* __restrict__ Wdst, ushort_t* __restrict__ BT,
                            int E, int total8, int degB, int cvtB) {
    int b = blockIdx.x;
    if (b < degB) {
        int e = b * 256 + threadIdx.x;
        if (e < E) rank[e] = atomicAdd(&deg[col[e]], 1);
    } else if (b < degB + cvtB) {
        int i = (b - degB) * 256 + threadIdx.x;
        if (i >= total8) return;
        float4 a = ((const float4*)x)[i * 2];
        float4 bb = ((const float4*)x)[i * 2 + 1];
        uint4 o;
        o.x = f2bf(a.x) | ((uint_t)f2bf(a.y) << 16);
        o.y = f2bf(a.z) | ((uint_t)f2bf(a.w) << 16);
        o.z = f2bf(bb.x) | ((uint_t)f2bf(bb.y) << 16);
        o.w = f2bf(bb.z) | ((uint_t)f2bf(bb.w) << 16);
        ((uint4*)xh)[i] = o;
    } else {
        int id = (b - degB - cvtB) * 256 + threadIdx.x;   // j*768+k
        if (id >= 256 * 768) return;
        int j = id / 768, k = id % 768;
        float v;
        if (k < 256)      v = Wself[(size_t)k * 256 + j];
        else if (k < 512) v = Wsrc [(size_t)(k - 256) * 256 + j];
        else              v = Wdst [(size_t)(k - 512) * 256 + j];
        BT[id] = f2bf(v);
    }
}

// ---------------------------------------------------------------------------
// Scan phase A: per-block (1024 elems) local exclusive scan into off,
// block totals into partials. 256 threads x int4.
// ---------------------------------------------------------------------------
__global__ __launch_bounds__(256) void scanA(const int* __restrict__ deg,
                                             int* __restrict__ off,
                                             int* __restrict__ partials, int n4) {
    __shared__ int wtot[4];
    const int tid = threadIdx.x, lane = tid & 63, wid = tid >> 6;
    int i4 = blockIdx.x * 256 + tid;
    int4 v = (i4 < n4) ? ((const int4*)deg)[i4] : make_int4(0, 0, 0, 0);
    int s = v.x + v.y + v.z + v.w;
    int incl = s;
    #pragma unroll
    for (int st = 1; st < 64; st <<= 1) {
        int t = __shfl_up(incl, st, 64);
        if (lane >= st) incl += t;
    }
    if (lane == 63) wtot[wid] = incl;
    __syncthreads();
    int wbase = 0;
    #pragma unroll
    for (int w = 0; w < 4; ++w) if (w < wid) wbase += wtot[w];
    int excl = incl - s + wbase;
    if (i4 < n4) {
        int4 o;
        o.x = excl; o.y = o.x + v.x; o.z = o.y + v.y; o.w = o.z + v.z;
        ((int4*)off)[i4] = o;
    }
    if (tid == 0) partials[blockIdx.x] = wtot[0] + wtot[1] + wtot[2] + wtot[3];
}

// ---------------------------------------------------------------------------
// Scan phase C: add exclusive block base (sum of earlier partials, <=64 blocks).
// ---------------------------------------------------------------------------
__global__ __launch_bounds__(256) void scanC(int* __restrict__ off,
                                             const int* __restrict__ partials, int n4) {
    __shared__ int base_s;
    const int tid = threadIdx.x;
    if (tid < 64) {
        int v = (tid < blockIdx.x) ? partials[tid] : 0;
        #pragma unroll
        for (int st = 32; st; st >>= 1) v += __shfl_down(v, st, 64);
        if (tid == 0) base_s = v;
    }
    __syncthreads();
    int base = base_s;
    int i4 = blockIdx.x * 256 + tid;
    if (i4 < n4) {
        int4 o = ((int4*)off)[i4];
        o.x += base; o.y += base; o.z += base; o.w += base;
        ((int4*)off)[i4] = o;
    }
}

// ---------------------------------------------------------------------------
// Atomic-free bucket fill using precomputed ranks.
// ---------------------------------------------------------------------------
__global__ void fill_kernel(const int* __restrict__ row, const int* __restrict__ col,
                            const int* __restrict__ rank, const int* __restrict__ off,
                            int* __restrict__ bucket, int E) {
    int e = blockIdx.x * blockDim.x + threadIdx.x;
    if (e >= E) return;
    bucket[off[col[e]] + rank[e]] = row[e];
}

// ---------------------------------------------------------------------------
// Per-node gather-sum over bf16 rows, fp32 accum, bf16 out. One wave/node,
// lane = 4 consecutive bf16 (8B). 4-wide unroll for MLP.
// ---------------------------------------------------------------------------
__global__ __launch_bounds__(256) void segsum_kernel(const ushort_t* __restrict__ xh,
                                                     const int* __restrict__ off,
                                                     const int* __restrict__ deg,
                                                     const int* __restrict__ bucket,
                                                     ushort_t* __restrict__ Gh, int N) {
    int node = blockIdx.x * 4 + (threadIdx.x >> 6);
    int lane = threadIdx.x & 63;
    if (node >= N) return;
    int start = off[node];
    int cnt = deg[node];
    float a0 = 0.f, a1 = 0.f, a2 = 0.f, a3 = 0.f;
    int i = 0;
    for (; i + 4 <= cnt; i += 4) {
        int r0 = bucket[start + i];
        int r1 = bucket[start + i + 1];
        int r2 = bucket[start + i + 2];
        int r3 = bucket[start + i + 3];
        ushort4 v0 = ((const ushort4*)(xh + (size_t)r0 * D))[lane];
        ushort4 v1 = ((const ushort4*)(xh + (size_t)r1 * D))[lane];
        ushort4 v2 = ((const ushort4*)(xh + (size_t)r2 * D))[lane];
        ushort4 v3 = ((const ushort4*)(xh + (size_t)r3 * D))[lane];
        a0 += (bf2f(v0.x) + bf2f(v1.x)) + (bf2f(v2.x) + bf2f(v3.x));
        a1 += (bf2f(v0.y) + bf2f(v1.y)) + (bf2f(v2.y) + bf2f(v3.y));
        a2 += (bf2f(v0.z) + bf2f(v1.z)) + (bf2f(v2.z) + bf2f(v3.z));
        a3 += (bf2f(v0.w) + bf2f(v1.w)) + (bf2f(v2.w) + bf2f(v3.w));
    }
    for (; i < cnt; ++i) {
        int r0 = bucket[start + i];
        ushort4 v0 = ((const ushort4*)(xh + (size_t)r0 * D))[lane];
        a0 += bf2f(v0.x); a1 += bf2f(v0.y); a2 += bf2f(v0.z); a3 += bf2f(v0.w);
    }
    ushort4 o;
    o.x = f2bf(a0); o.y = f2bf(a1); o.z = f2bf(a2); o.w = f2bf(a3);
    ((ushort4*)(Gh + (size_t)node * D))[lane] = o;
}

// ---------------------------------------------------------------------------
// bf16 MFMA GEMM, fragment-major LDS + global_load_lds (zero bank conflicts).
//   kt 0..7 : A=xh tile; acc1 += A@Wself-tile, acc2 += A@Wdst-tile (A reused)
//   kt 8..15: A=Gh tile; acc1 += A@Wsrc-tile
//   out = acc1 - deg*acc2 + bself + deg*(bsrc-bdst)
// LDS layout [group][lane][8 shorts]: DMA dest = base+lane*16; fragment read
// b128 at base+lane*16 -> conflict-free by construction.
// ---------------------------------------------------------------------------
__global__ __launch_bounds__(256, 2) void mfma_gemm(
    const ushort_t* __restrict__ xh, const ushort_t* __restrict__ Gh,
    const ushort_t* __restrict__ BT, const int* __restrict__ deg,
    const float* __restrict__ bsrc, const float* __restrict__ bdst,
    const float* __restrict__ bself, float* __restrict__ out, int N)
{
    __shared__ ushort_t As[8][64][8];   // 8 KB
    __shared__ ushort_t Bs[8][64][8];   // 8 KB
    __shared__ ushort_t Ds[8][64][8];   // 8 KB (Wdst tiles, kt<8)

    const int tid = threadIdx.x;
    const int lane = tid & 63, wave = tid >> 6;
    const int quad = lane >> 4, l15 = lane & 15;
    const int mg = (wave >> 1) * 4, ng = (wave & 1) * 4;   // fragment group bases
    const int mbase = blockIdx.x * 128, nbase = blockIdx.y * 128;

    // this wave stages groups ga0, ga1 of each tile
    const int ga0 = wave * 2, ga1 = ga0 + 1;
    int ar0 = mbase + ga0 * 16 + l15; if (ar0 >= N) ar0 = N - 1;
    int ar1 = mbase + ga1 * 16 + l15; if (ar1 >= N) ar1 = N - 1;
    const size_t aoff0 = (size_t)ar0 * 256 + quad * 8;
    const size_t aoff1 = (size_t)ar1 * 256 + quad * 8;
    const ushort_t* bp0 = BT + (size_t)(nbase + ga0 * 16 + l15) * 768 + quad * 8;
    const ushort_t* bp1 = BT + (size_t)(nbase + ga1 * 16 + l15) * 768 + quad * 8;

    floatx4 acc1[4][4] = {};
    floatx4 acc2[4][4] = {};

    for (int kt = 0; kt < 16; ++kt) {
        const ushort_t* Asrc = (kt < 8) ? xh : Gh;
        const int ka = (kt & 7) * 32;      // k-col within A source
        const int kb = kt * 32;            // k-col within BT (Wself then Wsrc)
        async16(Asrc + aoff0 + ka, &As[ga0][0][0]);
        async16(Asrc + aoff1 + ka, &As[ga1][0][0]);
        async16(bp0 + kb, &Bs[ga0][0][0]);
        async16(bp1 + kb, &Bs[ga1][0][0]);
        if (kt < 8) {
            async16(bp0 + 512 + kb, &Ds[ga0][0][0]);
            async16(bp1 + 512 + kb, &Ds[ga1][0][0]);
        }
        __syncthreads();

        short8 af[4], bfr[4];
        #pragma unroll
        for (int im = 0; im < 4; ++im)
            af[im] = *(const short8*)(&As[mg + im][lane][0]);
        #pragma unroll
        for (int in = 0; in < 4; ++in)
            bfr[in] = *(const short8*)(&Bs[ng + in][lane][0]);
        #pragma unroll
        for (int im = 0; im < 4; ++im)
            #pragma unroll
            for (int in = 0; in < 4; ++in)
                acc1[im][in] = __builtin_amdgcn_mfma_f32_16x16x32_bf16(
                    af[im], bfr[in], acc1[im][in], 0, 0, 0);
        if (kt < 8) {
            short8 df[4];
            #pragma unroll
            for (int in = 0; in < 4; ++in)
                df[in] = *(const short8*)(&Ds[ng + in][lane][0]);
            #pragma unroll
            for (int im = 0; im < 4; ++im)
                #pragma unroll
                for (int in = 0; in < 4; ++in)
                    acc2[im][in] = __builtin_amdgcn_mfma_f32_16x16x32_bf16(
                        af[im], df[in], acc2[im][in], 0, 0, 0);
        }
        __syncthreads();
    }

    // hoist deg for the 16 rows this thread writes
    float degv[4][4];
    #pragma unroll
    for (int im = 0; im < 4; ++im)
        #pragma unroll
        for (int r = 0; r < 4; ++r) {
            int gm = mbase + (wave >> 1) * 64 + im * 16 + quad * 4 + r;
            degv[im][r] = (gm < N) ? (float)deg[gm] : 0.f;
        }

    // C/D layout: col = lane&15, row = quad*4 + reg
    #pragma unroll
    for (int in = 0; in < 4; ++in) {
        int gn = nbase + (wave & 1) * 64 + in * 16 + l15;
        float bs = bself[gn];
        float db = bsrc[gn] - bdst[gn];
        #pragma unroll
        for (int im = 0; im < 4; ++im) {
            #pragma unroll
            for (int r = 0; r < 4; ++r) {
                int gm = mbase + (wave >> 1) * 64 + im * 16 + quad * 4 + r;
                if (gm < N) {
                    float d = degv[im][r];
                    out[(size_t)gm * 256 + gn] =
                        acc1[im][in][r] - d * acc2[im][in][r] + bs + d * db;
                }
            }
        }
    }
}

extern "C" void kernel_launch(void* const* d_in, const int* in_sizes, int n_in,
                              void* d_out, int out_size, void* d_ws, size_t ws_size,
                              hipStream_t stream) {
    const float* x     = (const float*)d_in[0];
    const int*   eidx  = (const int*)d_in[1];
    const float* Wsrc  = (const float*)d_in[2];
    const float* bsrc  = (const float*)d_in[3];
    const float* Wdst  = (const float*)d_in[4];
    const float* bdst  = (const float*)d_in[5];
    const float* Wself = (const float*)d_in[6];
    const float* bself = (const float*)d_in[7];
    float* out = (float*)d_out;

    const int N = in_sizes[0] / D;       // 50000
    const int E = in_sizes[1] / 2;       // 800000
    const int* row = eidx;
    const int* col = eidx + E;

    // ws layout: xh | Gh | BT | deg | off | partials | bucket
    // rank[] (E ints) is ALIASED onto Gh: dead before segsum writes Gh.
    char* p = (char*)d_ws;
    ushort_t* xh  = (ushort_t*)p;        p += (size_t)N * D * sizeof(ushort_t);
    ushort_t* Gh  = (ushort_t*)p;        int* rank = (int*)p;
                                         p += (size_t)N * D * sizeof(ushort_t);
    ushort_t* BT  = (ushort_t*)p;        p += (size_t)768 * 256 * sizeof(ushort_t);
    int* deg      = (int*)p;             p += (size_t)N * sizeof(int);
    int* off      = (int*)p;             p += (size_t)N * sizeof(int);
    int* partials = (int*)p;             p += 64 * sizeof(int);
    int* bucket   = (int*)p;

    hipMemsetAsync(deg, 0, (size_t)N * sizeof(int), stream);

    const int total8 = N * D / 8;                 // 1,600,000
    const int degB = (E + 255) / 256;             // 3125
    const int cvtB = (total8 + 255) / 256;        // 6250
    const int btB  = (256 * 768 + 255) / 256;     // 768
    prep_kernel<<<degB + cvtB + btB, 256, 0, stream>>>(col, deg, rank, x, xh,
                                                       Wself, Wsrc, Wdst, BT,
                                                       E, total8, degB, cvtB);
    const int n4 = N / 4;                         // 12500
    const int nblk = (n4 + 255) / 256;            // 49 (<= 64 required by scanC)
    scanA<<<nblk, 256, 0, stream>>>(deg, off, partials, n4);
    scanC<<<nblk, 256, 0, stream>>>(off, partials, n4);
    fill_kernel<<<(E + 255) / 256, 256, 0, stream>>>(row, col, rank, off, bucket, E);
    segsum_kernel<<<(N + 3) / 4, 256, 0, stream>>>(xh, off, deg, bucket, Gh, N);

    dim3 grid((N + 127) / 128, 2);
    mfma_gemm<<<grid, 256, 0, stream>>>(xh, Gh, BT, deg, bsrc, bdst, bself, out, N);
}